// Round 1
// baseline (3320.053 us; speedup 1.0000x reference)
//
#include <hip/hip_runtime.h>
#include <cmath>

#define TT 1024
#define BB 256
#define II 128
#define HH 256

// One workgroup per batch row b (rows are independent through the recurrence).
// Thread j owns output column j: holds V[j][:] (256 f32) and W[j][:] (128 f32)
// in registers; h and x live in double-buffered LDS and are read as uniform
// (broadcast) float4s. One barrier per timestep.
__global__ __launch_bounds__(256, 1)
void rnn_fused(const float* __restrict__ x,
               const float* __restrict__ W,
               const float* __restrict__ bW,
               const float* __restrict__ V,
               const float* __restrict__ bV,
               float* __restrict__ out)
{
    const int b = blockIdx.x;
    const int j = threadIdx.x;

    __shared__ float hbuf[2][HH];
    __shared__ float xbuf[2][II];

    // V row j and W row j into registers (one-time, L2-served, ~96 MB total)
    float4 Vreg[HH / 4];
    float4 Wreg[II / 4];
    {
        const float4* Vrow = reinterpret_cast<const float4*>(V + (size_t)j * HH);
#pragma unroll
        for (int k4 = 0; k4 < HH / 4; ++k4) Vreg[k4] = Vrow[k4];
        const float4* Wrow = reinterpret_cast<const float4*>(W + (size_t)j * II);
#pragma unroll
        for (int k4 = 0; k4 < II / 4; ++k4) Wreg[k4] = Wrow[k4];
    }
    const float bias = bW[j] + bV[j];

    hbuf[0][j] = 0.0f;
    if (j < II) xbuf[0][j] = x[(size_t)b * II + j];  // x[t=0][b][j]
    __syncthreads();

    float* __restrict__ seq = out;                          // (T,B,H)
    float* __restrict__ fin = out + (size_t)TT * BB * HH;   // (B,H)

    int p = 0;
    float h = 0.0f;
#pragma unroll 1
    for (int t = 0; t < TT; ++t) {
        // Prefetch next timestep's x row while we compute (hides HBM latency).
        float xn = 0.0f;
        if (j < II && t + 1 < TT)
            xn = x[((size_t)(t + 1) * BB + b) * II + j];

        const float4* h4 = reinterpret_cast<const float4*>(hbuf[p]);
        const float4* x4 = reinterpret_cast<const float4*>(xbuf[p]);

        // 8 independent accumulators: FMA dep-latency ~4cyc, issue 2cyc.
        float a0 = 0.f, a1 = 0.f, a2 = 0.f, a3 = 0.f;
        float a4 = 0.f, a5 = 0.f, a6 = 0.f, a7 = 0.f;

#pragma unroll
        for (int k4 = 0; k4 < HH / 4; k4 += 2) {
            float4 hv0 = h4[k4];
            float4 hv1 = h4[k4 + 1];
            float4 v0 = Vreg[k4];
            float4 v1 = Vreg[k4 + 1];
            a0 += hv0.x * v0.x; a1 += hv0.y * v0.y;
            a2 += hv0.z * v0.z; a3 += hv0.w * v0.w;
            a4 += hv1.x * v1.x; a5 += hv1.y * v1.y;
            a6 += hv1.z * v1.z; a7 += hv1.w * v1.w;
        }
#pragma unroll
        for (int k4 = 0; k4 < II / 4; k4 += 2) {
            float4 xv0 = x4[k4];
            float4 xv1 = x4[k4 + 1];
            float4 w0 = Wreg[k4];
            float4 w1 = Wreg[k4 + 1];
            a0 += xv0.x * w0.x; a1 += xv0.y * w0.y;
            a2 += xv0.z * w0.z; a3 += xv0.w * w0.w;
            a4 += xv1.x * w1.x; a5 += xv1.y * w1.y;
            a6 += xv1.z * w1.z; a7 += xv1.w * w1.w;
        }

        float acc = ((a0 + a1) + (a2 + a3)) + ((a4 + a5) + (a6 + a7)) + bias;
        h = tanhf(acc);

        seq[((size_t)t * BB + b) * HH + j] = h;
        hbuf[p ^ 1][j] = h;
        if (j < II) xbuf[p ^ 1][j] = xn;
        __syncthreads();
        p ^= 1;
    }
    fin[(size_t)b * HH + j] = h;
}

extern "C" void kernel_launch(void* const* d_in, const int* in_sizes, int n_in,
                              void* d_out, int out_size, void* d_ws, size_t ws_size,
                              hipStream_t stream)
{
    const float* x  = (const float*)d_in[0];
    const float* W  = (const float*)d_in[1];
    const float* bW = (const float*)d_in[2];
    const float* V  = (const float*)d_in[3];
    const float* bV = (const float*)d_in[4];
    float* out = (float*)d_out;

    rnn_fused<<<dim3(BB), dim3(HH), 0, stream>>>(x, W, bW, V, bV, out);
}

// Round 2
// 1437.092 us; speedup vs baseline: 2.3103x; 2.3103x over previous
//
#include <hip/hip_runtime.h>
#include <hip/hip_fp16.h>
#include <cmath>

#define TT 1024
#define BB 256
#define II 128
#define HH 256

typedef _Float16 h2 __attribute__((ext_vector_type(2)));

#if defined(__has_builtin)
#if __has_builtin(__builtin_amdgcn_fdot2)
#define FDOT2(a, b, c) __builtin_amdgcn_fdot2((a), (b), (c), false)
#endif
#endif
#ifndef FDOT2
#define FDOT2(a, b, c) ((c) + (float)(a)[0] * (float)(b)[0] + (float)(a)[1] * (float)(b)[1])
#endif

union F4H {
    float4 f4;
    h2 hh[4];
};

// One WG per batch row. Thread j owns output column j; V[j][:] and W[j][:]
// live in fp16 half2 registers (192 VGPRs -- fits, unlike the fp32 version
// which spilled ~150 floats/thread). h/x are fp16 in LDS, read as broadcast
// float4 (8 halfs per ds_read_b128). v_dot2_f32_f16 gives 2 MACs/instr with
// f32 accumulate.
__global__ __launch_bounds__(256, 1)
void rnn_fused_h(const float* __restrict__ x,
                 const float* __restrict__ W,
                 const float* __restrict__ bW,
                 const float* __restrict__ V,
                 const float* __restrict__ bV,
                 float* __restrict__ out)
{
    const int b = blockIdx.x;
    const int j = threadIdx.x;

    __shared__ __align__(16) _Float16 hbuf[2][HH];
    __shared__ __align__(16) _Float16 xbuf[2][II];

    h2 Vreg[HH / 2];  // 128 VGPRs
    h2 Wreg[II / 2];  // 64 VGPRs
    {
        const float4* Vrow = reinterpret_cast<const float4*>(V + (size_t)j * HH);
#pragma unroll
        for (int k = 0; k < HH / 4; ++k) {
            float4 v = Vrow[k];
            Vreg[2 * k]     = h2{(_Float16)v.x, (_Float16)v.y};
            Vreg[2 * k + 1] = h2{(_Float16)v.z, (_Float16)v.w};
        }
        const float4* Wrow = reinterpret_cast<const float4*>(W + (size_t)j * II);
#pragma unroll
        for (int k = 0; k < II / 4; ++k) {
            float4 w = Wrow[k];
            Wreg[2 * k]     = h2{(_Float16)w.x, (_Float16)w.y};
            Wreg[2 * k + 1] = h2{(_Float16)w.z, (_Float16)w.w};
        }
    }
    const float bias = bW[j] + bV[j];

    hbuf[0][j] = (_Float16)0.f;
    if (j < II) xbuf[0][j] = (_Float16)x[(size_t)b * II + j];
    __syncthreads();

    float* __restrict__ seq = out;                         // (T,B,H) fp32
    float* __restrict__ fin = out + (size_t)TT * BB * HH;  // (B,H) fp32

    int p = 0;
    float hf = 0.0f;
#pragma unroll 1
    for (int t = 0; t < TT; ++t) {
        // prefetch next x row (hides HBM latency under the dot2 chain)
        float xn = 0.0f;
        if (j < II && t + 1 < TT)
            xn = x[((size_t)(t + 1) * BB + b) * II + j];

        const float4* h4 = reinterpret_cast<const float4*>(hbuf[p]);
        const float4* x4 = reinterpret_cast<const float4*>(xbuf[p]);

        float a0 = 0.f, a1 = 0.f, a2 = 0.f, a3 = 0.f;
        float a4 = 0.f, a5 = 0.f, a6 = 0.f, a7 = 0.f;

#pragma unroll
        for (int k = 0; k < HH / 8; k += 2) {  // 32 b128 reads, 128 dot2
            F4H u0, u1;
            u0.f4 = h4[k];
            u1.f4 = h4[k + 1];
            a0 = FDOT2(u0.hh[0], Vreg[4 * k + 0], a0);
            a1 = FDOT2(u0.hh[1], Vreg[4 * k + 1], a1);
            a2 = FDOT2(u0.hh[2], Vreg[4 * k + 2], a2);
            a3 = FDOT2(u0.hh[3], Vreg[4 * k + 3], a3);
            a4 = FDOT2(u1.hh[0], Vreg[4 * k + 4], a4);
            a5 = FDOT2(u1.hh[1], Vreg[4 * k + 5], a5);
            a6 = FDOT2(u1.hh[2], Vreg[4 * k + 6], a6);
            a7 = FDOT2(u1.hh[3], Vreg[4 * k + 7], a7);
        }
#pragma unroll
        for (int k = 0; k < II / 8; k += 2) {  // 16 b128 reads, 64 dot2
            F4H u0, u1;
            u0.f4 = x4[k];
            u1.f4 = x4[k + 1];
            a0 = FDOT2(u0.hh[0], Wreg[4 * k + 0], a0);
            a1 = FDOT2(u0.hh[1], Wreg[4 * k + 1], a1);
            a2 = FDOT2(u0.hh[2], Wreg[4 * k + 2], a2);
            a3 = FDOT2(u0.hh[3], Wreg[4 * k + 3], a3);
            a4 = FDOT2(u1.hh[0], Wreg[4 * k + 4], a4);
            a5 = FDOT2(u1.hh[1], Wreg[4 * k + 5], a5);
            a6 = FDOT2(u1.hh[2], Wreg[4 * k + 6], a6);
            a7 = FDOT2(u1.hh[3], Wreg[4 * k + 7], a7);
        }

        float acc = ((a0 + a1) + (a2 + a3)) + ((a4 + a5) + (a6 + a7)) + bias;
        hf = tanhf(acc);

        seq[((size_t)t * BB + b) * HH + j] = hf;  // coalesced 1KB/WG store
        hbuf[p ^ 1][j] = (_Float16)hf;
        if (j < II) xbuf[p ^ 1][j] = (_Float16)xn;
        __syncthreads();
        p ^= 1;
    }
    fin[(size_t)b * HH + j] = hf;
}

extern "C" void kernel_launch(void* const* d_in, const int* in_sizes, int n_in,
                              void* d_out, int out_size, void* d_ws, size_t ws_size,
                              hipStream_t stream)
{
    const float* x  = (const float*)d_in[0];
    const float* W  = (const float*)d_in[1];
    const float* bW = (const float*)d_in[2];
    const float* V  = (const float*)d_in[3];
    const float* bV = (const float*)d_in[4];
    float* out = (float*)d_out;

    rnn_fused_h<<<dim3(BB), dim3(HH), 0, stream>>>(x, W, bW, V, bV, out);
}

// Round 4
// 1375.586 us; speedup vs baseline: 2.4136x; 1.0447x over previous
//
#include <hip/hip_runtime.h>
#include <hip/hip_fp16.h>
#include <cmath>

#define TT 1024
#define BB 256
#define II 128
#define HH 256

typedef _Float16 h2 __attribute__((ext_vector_type(2)));

#if defined(__has_builtin)
#if __has_builtin(__builtin_amdgcn_fdot2)
#define FDOT2(a, b, c) __builtin_amdgcn_fdot2((a), (b), (c), false)
#endif
#endif
#ifndef FDOT2
#define FDOT2(a, b, c) ((c) + (float)(a)[0] * (float)(b)[0] + (float)(a)[1] * (float)(b)[1])
#endif

union F4H {
    float4 f4;
    h2 hh[4];
};

// LDS-only barrier: the per-step h/x handoff goes through LDS, so we need
// lgkmcnt(0) + s_barrier -- NOT the vmcnt(0) drain __syncthreads() implies.
// The h_seq global stores stay in flight across steps (compiler inserts
// counted vmcnt waits only for store-source register reuse).
#define LDS_BARRIER()                                            \
    do {                                                         \
        asm volatile("s_waitcnt lgkmcnt(0)" ::: "memory");       \
        __builtin_amdgcn_s_barrier();                            \
        __builtin_amdgcn_sched_barrier(0);                       \
    } while (0)

// tanh(a) = 1 - 2/(e^{2a}+1), e^{2a} = 2^{a * 2*log2(e)}.
// v_exp_f32 + v_rcp_f32: ~5 instrs, exact at +/-inf, err ~1e-6.
__device__ __forceinline__ float fast_tanh(float a)
{
    float e = __builtin_amdgcn_exp2f(a * 2.8853900817779268f);  // 2^(2a*log2e)
    return 1.0f - 2.0f * __builtin_amdgcn_rcpf(e + 1.0f);
}

__global__ __launch_bounds__(256, 1)
void rnn_fused_h2(const float* __restrict__ x,
                  const float* __restrict__ W,
                  const float* __restrict__ bW,
                  const float* __restrict__ V,
                  const float* __restrict__ bV,
                  float* __restrict__ out)
{
    const int b = blockIdx.x;
    const int j = threadIdx.x;

    __shared__ __align__(16) _Float16 hbuf[2][HH];
    __shared__ __align__(16) _Float16 xbuf[2][II];

    h2 Vreg[HH / 2];  // 128 VGPRs
    h2 Wreg[II / 2];  // 64 VGPRs
    {
        const float4* Vrow = reinterpret_cast<const float4*>(V + (size_t)j * HH);
#pragma unroll
        for (int k = 0; k < HH / 4; ++k) {
            float4 v = Vrow[k];
            Vreg[2 * k]     = h2{(_Float16)v.x, (_Float16)v.y};
            Vreg[2 * k + 1] = h2{(_Float16)v.z, (_Float16)v.w};
        }
        const float4* Wrow = reinterpret_cast<const float4*>(W + (size_t)j * II);
#pragma unroll
        for (int k = 0; k < II / 4; ++k) {
            float4 w = Wrow[k];
            Wreg[2 * k]     = h2{(_Float16)w.x, (_Float16)w.y};
            Wreg[2 * k + 1] = h2{(_Float16)w.z, (_Float16)w.w};
        }
    }
    const float bias = bW[j] + bV[j];

    hbuf[0][j] = (_Float16)0.f;
    if (j < II) xbuf[0][j] = (_Float16)x[(size_t)b * II + j];
    __syncthreads();

    float* __restrict__ seq = out;                         // (T,B,H) fp32
    float* __restrict__ fin = out + (size_t)TT * BB * HH;  // (B,H) fp32

    int p = 0;
    float hf = 0.0f;
#pragma unroll 1
    for (int t = 0; t < TT; ++t) {
        // prefetch next x row (global load stays in flight across the step)
        float xn = 0.0f;
        if (j < II && t + 1 < TT)
            xn = x[((size_t)(t + 1) * BB + b) * II + j];

        const float4* h4 = reinterpret_cast<const float4*>(hbuf[p]);
        const float4* x4 = reinterpret_cast<const float4*>(xbuf[p]);

        float a0 = 0.f, a1 = 0.f, a2 = 0.f, a3 = 0.f;
        float a4 = 0.f, a5 = 0.f, a6 = 0.f, a7 = 0.f;

#pragma unroll
        for (int k = 0; k < HH / 8; k += 2) {  // 32 b128 broadcast reads, 128 dot2
            F4H u0, u1;
            u0.f4 = h4[k];
            u1.f4 = h4[k + 1];
            a0 = FDOT2(u0.hh[0], Vreg[4 * k + 0], a0);
            a1 = FDOT2(u0.hh[1], Vreg[4 * k + 1], a1);
            a2 = FDOT2(u0.hh[2], Vreg[4 * k + 2], a2);
            a3 = FDOT2(u0.hh[3], Vreg[4 * k + 3], a3);
            a4 = FDOT2(u1.hh[0], Vreg[4 * k + 4], a4);
            a5 = FDOT2(u1.hh[1], Vreg[4 * k + 5], a5);
            a6 = FDOT2(u1.hh[2], Vreg[4 * k + 6], a6);
            a7 = FDOT2(u1.hh[3], Vreg[4 * k + 7], a7);
        }
#pragma unroll
        for (int k = 0; k < II / 8; k += 2) {  // 16 b128 broadcast reads, 64 dot2
            F4H u0, u1;
            u0.f4 = x4[k];
            u1.f4 = x4[k + 1];
            a0 = FDOT2(u0.hh[0], Wreg[4 * k + 0], a0);
            a1 = FDOT2(u0.hh[1], Wreg[4 * k + 1], a1);
            a2 = FDOT2(u0.hh[2], Wreg[4 * k + 2], a2);
            a3 = FDOT2(u0.hh[3], Wreg[4 * k + 3], a3);
            a4 = FDOT2(u1.hh[0], Wreg[4 * k + 4], a4);
            a5 = FDOT2(u1.hh[1], Wreg[4 * k + 5], a5);
            a6 = FDOT2(u1.hh[2], Wreg[4 * k + 6], a6);
            a7 = FDOT2(u1.hh[3], Wreg[4 * k + 7], a7);
        }

        float acc = ((a0 + a1) + (a2 + a3)) + ((a4 + a5) + (a6 + a7)) + bias;
        hf = fast_tanh(acc);

        seq[((size_t)t * BB + b) * HH + j] = hf;  // coalesced, fire-and-forget
        hbuf[p ^ 1][j] = (_Float16)hf;
        if (j < II) xbuf[p ^ 1][j] = (_Float16)xn;
        LDS_BARRIER();
        p ^= 1;
    }
    fin[(size_t)b * HH + j] = hf;
}

extern "C" void kernel_launch(void* const* d_in, const int* in_sizes, int n_in,
                              void* d_out, int out_size, void* d_ws, size_t ws_size,
                              hipStream_t stream)
{
    const float* x  = (const float*)d_in[0];
    const float* W  = (const float*)d_in[1];
    const float* bW = (const float*)d_in[2];
    const float* V  = (const float*)d_in[3];
    const float* bV = (const float*)d_in[4];
    float* out = (float*)d_out;

    rnn_fused_h2<<<dim3(BB), dim3(HH), 0, stream>>>(x, W, bW, V, bV, out);
}

// Round 5
// 1205.503 us; speedup vs baseline: 2.7541x; 1.1411x over previous
//
#include <hip/hip_runtime.h>
#include <hip/hip_fp16.h>

#define TT 1024
#define BB 256
#define II 128
#define HH 256

typedef _Float16 h2 __attribute__((ext_vector_type(2)));

static __device__ __forceinline__ float fdot2(h2 a, h2 b, float c)
{
#if defined(__has_builtin) && __has_builtin(__builtin_amdgcn_fdot2)
    return __builtin_amdgcn_fdot2(a, b, c, false);
#else
    return c + (float)a[0] * (float)b[0] + (float)a[1] * (float)b[1];
#endif
}

union UH { unsigned u; h2 h; };
static __device__ __forceinline__ h2 as_h2(unsigned v) { UH t; t.u = v; return t.h; }

// LDS-only barrier (h/x handoff is pure LDS; h_seq stores stay in flight).
#define LDS_BARRIER()                                            \
    do {                                                         \
        asm volatile("s_waitcnt lgkmcnt(0)" ::: "memory");       \
        __builtin_amdgcn_s_barrier();                            \
        __builtin_amdgcn_sched_barrier(0);                       \
    } while (0)

// tanh(a) = 1 - 2/(2^(2a*log2e)+1): v_exp_f32 + v_rcp_f32, err ~1e-6.
__device__ __forceinline__ float fast_tanh(float a)
{
    float e = __builtin_amdgcn_exp2f(a * 2.8853900817779268f);
    return 1.0f - 2.0f * __builtin_amdgcn_rcpf(e + 1.0f);
}

// One WG (4 waves) per batch row. Thread j owns output column j with V[j][:],
// W[j][:] in fp16 registers. Per step, each wave pulls the whole h (512 B)
// with ONE ds_read_b64 per lane-slice (lane l -> h[4l..4l+3]) and x with one
// ds_read_b32, then redistributes via v_readlane -> SGPR feeding v_dot2
// directly (VALU pipe), instead of 48 broadcast ds_read_b128 per lane which
// saturated the per-CU LDS pipe (192 LDS instr/CU/step ~ 2300 cyc).
__global__ __launch_bounds__(256, 1)
void rnn_readlane(const float* __restrict__ x,
                  const float* __restrict__ W,
                  const float* __restrict__ bW,
                  const float* __restrict__ V,
                  const float* __restrict__ bV,
                  float* __restrict__ out)
{
    const int b = blockIdx.x;
    const int j = threadIdx.x;
    const int l = j & 63;  // lane within wave

    __shared__ __align__(16) _Float16 hbuf[2][HH];
    __shared__ __align__(16) _Float16 xbuf[2][II];

    h2 Vreg[HH / 2];  // 128 VGPRs
    h2 Wreg[II / 2];  // 64 VGPRs
    {
        const float4* Vrow = reinterpret_cast<const float4*>(V + (size_t)j * HH);
#pragma unroll
        for (int k = 0; k < HH / 4; ++k) {
            float4 v = Vrow[k];
            Vreg[2 * k]     = h2{(_Float16)v.x, (_Float16)v.y};
            Vreg[2 * k + 1] = h2{(_Float16)v.z, (_Float16)v.w};
        }
        const float4* Wrow = reinterpret_cast<const float4*>(W + (size_t)j * II);
#pragma unroll
        for (int k = 0; k < II / 4; ++k) {
            float4 w = Wrow[k];
            Wreg[2 * k]     = h2{(_Float16)w.x, (_Float16)w.y};
            Wreg[2 * k + 1] = h2{(_Float16)w.z, (_Float16)w.w};
        }
    }
    const float bias = bW[j] + bV[j];

    hbuf[0][j] = (_Float16)0.f;
    if (j < II) xbuf[0][j] = (_Float16)x[(size_t)b * II + j];
    __syncthreads();

    float* __restrict__ seq = out;                         // (T,B,H) fp32
    float* __restrict__ fin = out + (size_t)TT * BB * HH;  // (B,H) fp32

    int p = 0;
    float hf = 0.0f;
#pragma unroll 1
    for (int t = 0; t < TT; ++t) {
        // prefetch next x row (stays in flight under the dot chain)
        float xn = 0.0f;
        if (j < II && t + 1 < TT)
            xn = x[((size_t)(t + 1) * BB + b) * II + j];

        // lane-sliced reads: whole h = 64 lanes x 8B, whole x = 64 lanes x 4B
        const uint2* hp = reinterpret_cast<const uint2*>(&hbuf[p][0]);
        const unsigned* xp = reinterpret_cast<const unsigned*>(&xbuf[p][0]);
        uint2 hv = hp[l];       // h[4l .. 4l+3]
        unsigned xv = xp[l];    // x[2l .. 2l+1]

        float a0 = 0.f, a1 = 0.f, a2 = 0.f, a3 = 0.f;

        // V part: 128 readlane + 128 dot2 (SGPR src0)
#pragma unroll
        for (int g = 0; g < 64; g += 2) {
            unsigned s00 = (unsigned)__builtin_amdgcn_readlane((int)hv.x, g);
            unsigned s01 = (unsigned)__builtin_amdgcn_readlane((int)hv.y, g);
            unsigned s10 = (unsigned)__builtin_amdgcn_readlane((int)hv.x, g + 1);
            unsigned s11 = (unsigned)__builtin_amdgcn_readlane((int)hv.y, g + 1);
            a0 = fdot2(as_h2(s00), Vreg[2 * g + 0], a0);
            a1 = fdot2(as_h2(s01), Vreg[2 * g + 1], a1);
            a2 = fdot2(as_h2(s10), Vreg[2 * g + 2], a2);
            a3 = fdot2(as_h2(s11), Vreg[2 * g + 3], a3);
        }
        // W part: 64 readlane + 64 dot2
#pragma unroll
        for (int g = 0; g < 64; g += 2) {
            unsigned s0 = (unsigned)__builtin_amdgcn_readlane((int)xv, g);
            unsigned s1 = (unsigned)__builtin_amdgcn_readlane((int)xv, g + 1);
            a0 = fdot2(as_h2(s0), Wreg[g], a0);
            a1 = fdot2(as_h2(s1), Wreg[g + 1], a1);
        }

        float acc = ((a0 + a1) + (a2 + a3)) + bias;
        hf = fast_tanh(acc);

        seq[((size_t)t * BB + b) * HH + j] = hf;  // coalesced, fire-and-forget
        hbuf[p ^ 1][j] = (_Float16)hf;
        if (j < II) xbuf[p ^ 1][j] = (_Float16)xn;
        LDS_BARRIER();
        p ^= 1;
    }
    fin[(size_t)b * HH + j] = hf;
}

extern "C" void kernel_launch(void* const* d_in, const int* in_sizes, int n_in,
                              void* d_out, int out_size, void* d_ws, size_t ws_size,
                              hipStream_t stream)
{
    const float* x  = (const float*)d_in[0];
    const float* W  = (const float*)d_in[1];
    const float* bW = (const float*)d_in[2];
    const float* V  = (const float*)d_in[3];
    const float* bV = (const float*)d_in[4];
    float* out = (float*)d_out;

    rnn_readlane<<<dim3(BB), dim3(HH), 0, stream>>>(x, W, bW, V, bV, out);
}

// Round 7
// 900.720 us; speedup vs baseline: 3.6860x; 1.3384x over previous
//
#include <hip/hip_runtime.h>
#include <hip/hip_fp16.h>

#define TT 1024
#define BB 256
#define II 128
#define HH 256

typedef _Float16 h2 __attribute__((ext_vector_type(2)));

union HU { h2 h; unsigned u; };
static __device__ __forceinline__ h2 as_h2(unsigned v) { HU t; t.u = v; return t.h; }
static __device__ __forceinline__ unsigned pack2(float a, float b)
{
    HU t; t.h = h2{(_Float16)a, (_Float16)b}; return t.u;
}
static __device__ __forceinline__ float fdot2u(unsigned a, unsigned b, float c)
{
    return __builtin_amdgcn_fdot2(as_h2(a), as_h2(b), c, false);
}

// LDS-only barrier (h/x/pbuf handoff is pure LDS; global stores stay in flight).
#define LDS_BARRIER()                                            \
    do {                                                         \
        asm volatile("s_waitcnt lgkmcnt(0)" ::: "memory");       \
        __builtin_amdgcn_s_barrier();                            \
        __builtin_amdgcn_sched_barrier(0);                       \
    } while (0)

// tanh(a) = 1 - 2/(2^(2a*log2e)+1): v_exp_f32 + v_rcp_f32, err ~1e-6.
__device__ __forceinline__ float fast_tanh(float a)
{
    float e = __builtin_amdgcn_exp2f(a * 2.8853900817779268f);
    return 1.0f - 2.0f * __builtin_amdgcn_rcpf(e + 1.0f);
}

// One WG (4 waves) per batch row. Wave w owns K-slice w; thread (lane l, wave w)
// owns outputs j = 4l..4l+3 restricted to k in [64w,64w+64) (V) / [32w,32w+32) (W).
// Each broadcast h-pair (readlane, wave-uniform lane index) feeds FOUR dot2s
// (4x feed reuse vs R4's 1x -> 330 instr/step/wave vs 845).
// Partials reduce through pbuf[4][HH] in LDS; the xW(t+1) phase is computed
// between the two barriers, hiding the pbuf read latency.
__global__ __launch_bounds__(256, 1)
void rnn_splitk(const float* __restrict__ x,
                const float* __restrict__ W,
                const float* __restrict__ bW,
                const float* __restrict__ V,
                const float* __restrict__ bV,
                float* __restrict__ out)
{
    const int b   = blockIdx.x;
    const int tid = threadIdx.x;
    const int l   = tid & 63;
    // wave id as a PROVABLY uniform value (readfirstlane) so readlane's lane
    // index is SGPR-uniform (avoids a waterfall lowering).
    const int w   = (__builtin_amdgcn_readfirstlane(tid) >> 6) & 3;
    const int kb  = 16 * w;  // lane base holding this wave's K-slice pairs

    __shared__ __align__(16) _Float16 hbuf[HH];
    __shared__ __align__(16) _Float16 xbuf[II];
    __shared__ __align__(16) float    pbuf[4][HH];

    // Per-thread weights: V[4 outs][K-slice 64] as 128 packed regs,
    // W[4 outs][K-slice 32] as 64 packed regs.
    unsigned Vreg[4][32];
    unsigned Wreg[4][16];
#pragma unroll
    for (int c = 0; c < 4; ++c) {
        const int j = 4 * l + c;
        const float* vr = V + (size_t)j * HH + 64 * w;
#pragma unroll
        for (int m = 0; m < 32; ++m) Vreg[c][m] = pack2(vr[2 * m], vr[2 * m + 1]);
        const float* wr = W + (size_t)j * II + 32 * w;
#pragma unroll
        for (int m = 0; m < 16; ++m) Wreg[c][m] = pack2(wr[2 * m], wr[2 * m + 1]);
    }
    const float bias = bW[tid] + bV[tid];

    hbuf[tid] = (_Float16)0.f;
    if (tid < II) xbuf[tid] = (_Float16)x[(size_t)b * II + tid];
    __syncthreads();

    float* __restrict__ seq = out;                         // (T,B,H) fp32
    float* __restrict__ fin = out + (size_t)TT * BB * HH;  // (B,H) fp32

    // Prologue X-phase: xsave = W-partials of x[0].
    float xsave[4] = {0.f, 0.f, 0.f, 0.f};
    {
        unsigned xv = reinterpret_cast<const unsigned*>(xbuf)[l];
#pragma unroll
        for (int i = 0; i < 16; ++i) {
            unsigned s = (unsigned)__builtin_amdgcn_readlane((int)xv, kb + i);
#pragma unroll
            for (int c = 0; c < 4; ++c) xsave[c] = fdot2u(s, Wreg[c][i], xsave[c]);
        }
    }
    // h(–1) = 0, distributed: lane l holds h[4l..4l+3].
    uint2 hv = reinterpret_cast<const uint2*>(hbuf)[l];

    // Prefetch x[1].
    float xn = 0.f;
    if (tid < II && 1 < TT) xn = x[((size_t)1 * BB + b) * II + tid];

    float hf = 0.f;
#pragma unroll 1
    for (int t = 0; t < TT; ++t) {
        // ---- V phase: h(t-1) . V^T, this wave's K-slice, 4 outputs ----
        float va[4][2] = {{0.f,0.f},{0.f,0.f},{0.f,0.f},{0.f,0.f}};
#pragma unroll
        for (int i = 0; i < 16; ++i) {
            unsigned s0 = (unsigned)__builtin_amdgcn_readlane((int)hv.x, kb + i);
            unsigned s1 = (unsigned)__builtin_amdgcn_readlane((int)hv.y, kb + i);
#pragma unroll
            for (int c = 0; c < 4; ++c) {
                va[c][0] = fdot2u(s0, Vreg[c][2 * i],     va[c][0]);
                va[c][1] = fdot2u(s1, Vreg[c][2 * i + 1], va[c][1]);
            }
        }
        float4 tot;
        tot.x = va[0][0] + va[0][1] + xsave[0];
        tot.y = va[1][0] + va[1][1] + xsave[1];
        tot.z = va[2][0] + va[2][1] + xsave[2];
        tot.w = va[3][0] + va[3][1] + xsave[3];
        *reinterpret_cast<float4*>(&pbuf[w][4 * l]) = tot;  // contiguous b128

        // Stage x[t+1] (loaded last iter), issue load of x[t+2].
        if (t + 1 < TT && tid < II) xbuf[tid] = (_Float16)xn;
        float xn2 = 0.f;
        if (t + 2 < TT && tid < II) xn2 = x[((size_t)(t + 2) * BB + b) * II + tid];

        LDS_BARRIER();  // pbuf + xbuf visible

        // Issue pbuf reads early (latency hides under the X phase).
        float p0 = pbuf[0][tid];
        float p1 = pbuf[1][tid];
        float p2 = pbuf[2][tid];
        float p3 = pbuf[3][tid];

        // ---- X phase for t+1: xsave = W-partials of x[t+1] ----
        if (t + 1 < TT) {
            unsigned xv = reinterpret_cast<const unsigned*>(xbuf)[l];
            xsave[0] = xsave[1] = xsave[2] = xsave[3] = 0.f;
#pragma unroll
            for (int i = 0; i < 16; ++i) {
                unsigned s = (unsigned)__builtin_amdgcn_readlane((int)xv, kb + i);
#pragma unroll
                for (int c = 0; c < 4; ++c) xsave[c] = fdot2u(s, Wreg[c][i], xsave[c]);
            }
        }

        // ---- finalize output `tid` ----
        float r = ((p0 + p1) + (p2 + p3)) + bias;
        hf = fast_tanh(r);
        seq[((size_t)t * BB + b) * HH + tid] = hf;  // coalesced, fire-and-forget
        hbuf[tid] = (_Float16)hf;

        LDS_BARRIER();  // h(t) visible
        hv = reinterpret_cast<const uint2*>(hbuf)[l];
        xn = xn2;
    }
    fin[(size_t)b * HH + tid] = hf;
}

extern "C" void kernel_launch(void* const* d_in, const int* in_sizes, int n_in,
                              void* d_out, int out_size, void* d_ws, size_t ws_size,
                              hipStream_t stream)
{
    const float* x  = (const float*)d_in[0];
    const float* W  = (const float*)d_in[1];
    const float* bW = (const float*)d_in[2];
    const float* V  = (const float*)d_in[3];
    const float* bV = (const float*)d_in[4];
    float* out = (float*)d_out;

    rnn_splitk<<<dim3(BB), dim3(HH), 0, stream>>>(x, W, bW, V, bV, out);
}

// Round 9
// 888.930 us; speedup vs baseline: 3.7349x; 1.0133x over previous
//
#include <hip/hip_runtime.h>
#include <hip/hip_fp16.h>

#define TT 1024
#define BB 256
#define II 128
#define HH 256

typedef _Float16 h2 __attribute__((ext_vector_type(2)));

union HU { h2 h; unsigned u; };
static __device__ __forceinline__ h2 as_h2(unsigned v) { HU t; t.u = v; return t.h; }
static __device__ __forceinline__ unsigned pack2(float a, float b)
{
    HU t; t.h = h2{(_Float16)a, (_Float16)b}; return t.u;
}
static __device__ __forceinline__ float fdot2u(unsigned a, unsigned b, float c)
{
    return __builtin_amdgcn_fdot2(as_h2(a), as_h2(b), c, false);
}

// LDS-only barrier (h/x/pbuf handoff is pure LDS; global stores stay in flight).
#define LDS_BARRIER()                                            \
    do {                                                         \
        asm volatile("s_waitcnt lgkmcnt(0)" ::: "memory");       \
        __builtin_amdgcn_s_barrier();                            \
        __builtin_amdgcn_sched_barrier(0);                       \
    } while (0)

// tanh(a) = 1 - 2/(2^(2a*log2e)+1): v_exp_f32 + v_rcp_f32, err ~1e-6.
__device__ __forceinline__ float fast_tanh(float a)
{
    float e = __builtin_amdgcn_exp2f(a * 2.8853900817779268f);
    return 1.0f - 2.0f * __builtin_amdgcn_rcpf(e + 1.0f);
}

// One 512-thread WG (8 waves) per batch row -> 2 waves/SIMD so VALU stalls
// overlap (R6 was 1 wave/SIMD, 59% VALUBusy, ~930 stall cyc/step).
// Wave w owns K-slice w: k in [32w,32w+32) of V, [16w,16w+16) of W.
// Thread (lane l) owns outputs 4l..4l+3 -> Vreg[4][16]+Wreg[4][8] = 96 VGPRs.
// Each readlane feed serves 4 dot2s. 8 partials reduce through pbuf in LDS.
// Finalize runs in waves 0-3; wave 4+w shares its SIMD with wave w, so each
// SIMD pairs one finalizer with one idler -- balanced.
__global__ __launch_bounds__(512, 2)
void rnn_splitk8(const float* __restrict__ x,
                 const float* __restrict__ W,
                 const float* __restrict__ bW,
                 const float* __restrict__ V,
                 const float* __restrict__ bV,
                 float* __restrict__ out)
{
    const int b   = blockIdx.x;
    const int tid = threadIdx.x;
    const int l   = tid & 63;
    // wave id as provably-uniform SGPR so readlane's index is uniform.
    const int w   = (__builtin_amdgcn_readfirstlane(tid) >> 6) & 7;
    const int lb  = 8 * w;  // lanes holding this wave's K-slice

    __shared__ __align__(16) _Float16 hbuf[HH];
    __shared__ __align__(16) _Float16 xbuf[II];
    __shared__ __align__(16) float    pbuf[8][HH];

    // Per-thread weights for 4 outputs x this wave's K-slice.
    unsigned Vreg[4][16];  // V[4l+c][32w + 2m, 2m+1]
    unsigned Wreg[4][8];   // W[4l+c][16w + 2m, 2m+1]
#pragma unroll
    for (int c = 0; c < 4; ++c) {
        const int j = 4 * l + c;
        const float* vr = V + (size_t)j * HH + 32 * w;
#pragma unroll
        for (int m = 0; m < 16; ++m) Vreg[c][m] = pack2(vr[2 * m], vr[2 * m + 1]);
        const float* wr = W + (size_t)j * II + 16 * w;
#pragma unroll
        for (int m = 0; m < 8; ++m) Wreg[c][m] = pack2(wr[2 * m], wr[2 * m + 1]);
    }
    const float bias = (tid < HH) ? (bW[tid] + bV[tid]) : 0.f;

    if (tid < HH) hbuf[tid] = (_Float16)0.f;
    if (tid < II) xbuf[tid] = (_Float16)x[(size_t)b * II + tid];
    __syncthreads();

    float* __restrict__ seq = out;                         // (T,B,H) fp32
    float* __restrict__ fin = out + (size_t)TT * BB * HH;  // (B,H) fp32

    // Prologue X-phase: xsave = this wave's W-partials of x[0].
    float xsave[4] = {0.f, 0.f, 0.f, 0.f};
    {
        unsigned xv = reinterpret_cast<const unsigned*>(xbuf)[l];
#pragma unroll
        for (int i = 0; i < 8; ++i) {
            unsigned s = (unsigned)__builtin_amdgcn_readlane((int)xv, lb + i);
#pragma unroll
            for (int c = 0; c < 4; ++c) xsave[c] = fdot2u(s, Wreg[c][i], xsave[c]);
        }
    }
    // lane l holds h[4l..4l+3] as two packed pairs.
    uint2 hv = reinterpret_cast<const uint2*>(hbuf)[l];

    float xn = 0.f;
    if (tid < II && 1 < TT) xn = x[((size_t)1 * BB + b) * II + tid];

    float hf = 0.f;
#pragma unroll 1
    for (int t = 0; t < TT; ++t) {
        // ---- V phase: this wave's K-slice, 4 outputs (16 rl + 64 dot2) ----
        float va[4][2] = {{0.f,0.f},{0.f,0.f},{0.f,0.f},{0.f,0.f}};
#pragma unroll
        for (int i2 = 0; i2 < 8; ++i2) {
            unsigned s0 = (unsigned)__builtin_amdgcn_readlane((int)hv.x, lb + i2);
            unsigned s1 = (unsigned)__builtin_amdgcn_readlane((int)hv.y, lb + i2);
#pragma unroll
            for (int c = 0; c < 4; ++c) {
                va[c][0] = fdot2u(s0, Vreg[c][2 * i2],     va[c][0]);
                va[c][1] = fdot2u(s1, Vreg[c][2 * i2 + 1], va[c][1]);
            }
        }
        float4 tot;
        tot.x = va[0][0] + va[0][1] + xsave[0];
        tot.y = va[1][0] + va[1][1] + xsave[1];
        tot.z = va[2][0] + va[2][1] + xsave[2];
        tot.w = va[3][0] + va[3][1] + xsave[3];
        *reinterpret_cast<float4*>(&pbuf[w][4 * l]) = tot;  // contiguous b128

        // Stage x[t+1], issue load of x[t+2].
        if (t + 1 < TT && tid < II) xbuf[tid] = (_Float16)xn;
        float xn2 = 0.f;
        if (t + 2 < TT && tid < II) xn2 = x[((size_t)(t + 2) * BB + b) * II + tid];

        LDS_BARRIER();  // pbuf + xbuf visible

        // Issue pbuf reads early (finalizer threads only).
        float p0 = 0.f, p1 = 0.f, p2 = 0.f, p3 = 0.f;
        float p4 = 0.f, p5 = 0.f, p6 = 0.f, p7 = 0.f;
        if (tid < HH) {
            p0 = pbuf[0][tid]; p1 = pbuf[1][tid];
            p2 = pbuf[2][tid]; p3 = pbuf[3][tid];
            p4 = pbuf[4][tid]; p5 = pbuf[5][tid];
            p6 = pbuf[6][tid]; p7 = pbuf[7][tid];
        }

        // ---- X phase for t+1 (all waves; hides pbuf read latency) ----
        if (t + 1 < TT) {
            unsigned xv = reinterpret_cast<const unsigned*>(xbuf)[l];
            xsave[0] = xsave[1] = xsave[2] = xsave[3] = 0.f;
#pragma unroll
            for (int i = 0; i < 8; ++i) {
                unsigned s = (unsigned)__builtin_amdgcn_readlane((int)xv, lb + i);
#pragma unroll
                for (int c = 0; c < 4; ++c) xsave[c] = fdot2u(s, Wreg[c][i], xsave[c]);
            }
        }

        // ---- finalize output `tid` (waves 0-3) ----
        if (tid < HH) {
            float r = (((p0 + p1) + (p2 + p3)) + ((p4 + p5) + (p6 + p7))) + bias;
            hf = fast_tanh(r);
            seq[((size_t)t * BB + b) * HH + tid] = hf;  // fire-and-forget
            hbuf[tid] = (_Float16)hf;
        }

        LDS_BARRIER();  // h(t) visible
        hv = reinterpret_cast<const uint2*>(hbuf)[l];
        xn = xn2;
    }
    if (tid < HH) fin[(size_t)b * HH + tid] = hf;
}

extern "C" void kernel_launch(void* const* d_in, const int* in_sizes, int n_in,
                              void* d_out, int out_size, void* d_ws, size_t ws_size,
                              hipStream_t stream)
{
    const float* x  = (const float*)d_in[0];
    const float* W  = (const float*)d_in[1];
    const float* bW = (const float*)d_in[2];
    const float* V  = (const float*)d_in[3];
    const float* bV = (const float*)d_in[4];
    float* out = (float*)d_out;

    rnn_splitk8<<<dim3(BB), dim3(512), 0, stream>>>(x, W, bW, V, bV, out);
}